// Round 5
// baseline (321.446 us; speedup 1.0000x reference)
//
#include <hip/hip_runtime.h>
#include <hip/hip_cooperative_groups.h>
#include <math.h>

namespace cg = cooperative_groups;

#define NN 1024
#define CC 256
#define TT 64
#define RPB 8   // rows per block in the mean phase (256 blocks x 8 = 2048)

// async global->LDS, 16B per lane. LDS dest is wave-uniform base + lane*16;
// global src is per-lane. Zero VGPR cost per outstanding load -> the
// compiler cannot collapse the pipeline.
#define AS1 __attribute__((address_space(1)))
#define AS3 __attribute__((address_space(3)))
static __device__ __forceinline__ void gload_lds16(const float* g, float4* l) {
  __builtin_amdgcn_global_load_lds((const AS1 void*)g, (AS3 void*)l, 16, 0, 0);
}

// ---- shared-memory overlays (phases reuse the same 142 KB of LDS) ----
struct MeanSM {
  float4 buf[2][TT][CC / 4];   // 2 x 64 KB row double-buffer
  float4 red[2][7][64];        // 14 KB cross-wave combine, parity-buffered
};
struct DistSM {
  float4 tAX[2][64][16];
  float4 tAY[2][64][16];
  float4 tBX[2][64][16];
  float4 tBY[2][64][16];
  float redp[3][8];
};
#define SMEM_BYTES (sizeof(MeanSM) > sizeof(DistSM) ? sizeof(MeanSM) : sizeof(DistSM))

// =====================================================================
// FUSED single cooperative kernel: mean+norm -> grid sync -> pairwise
// dist tiles -> grid sync -> finalize. Eliminates 2 kernel-launch
// boundaries (~80us of non-kernel time in rounds 0-4: sum(kernel durs)
// ~88us vs bench 173us). Phase internals are the proven round-4 bodies.
// =====================================================================
__global__ __launch_bounds__(512) void fused_kernel(
    const float* __restrict__ in0, const float* __restrict__ in1,
    float* __restrict__ x, float* __restrict__ y,
    float* __restrict__ nx, float* __restrict__ ny,
    float* __restrict__ Rxp, float* __restrict__ Ryp,
    float* __restrict__ pab, float* __restrict__ paa, float* __restrict__ pbb,
    float* __restrict__ out) {
  __shared__ __align__(16) char smraw[SMEM_BYTES];
  cg::grid_group grid = cg::this_grid();
  int tid = threadIdx.x;

  // ---------------- phase 1: time-mean + row norm ----------------
  // 8 waves/block; wave w owns t-slices [w*8, w*8+8) of each row. Rows
  // double-buffered in LDS; 8 async loads/wave/row, 2 rows in flight
  // (16 outstanding/wave = 128 KB/CU). Raw s_barrier (lgkmcnt only, no
  // vmcnt drain) for the cross-wave combine; red[] parity-buffered.
  {
    MeanSM* sm = (MeanSM*)smraw;
    int w = tid >> 6;          // 0..7
    int lane = tid & 63;
    int tb = w * 8;            // this wave's first time-step
    int base = blockIdx.x * RPB;

    #define ISSUE_ROW(r)                                                      \
      do {                                                                    \
        int pair_ = base + (r);                                               \
        const float* in_ = ((pair_ >> 10) ? in1 : in0) +                      \
                           (size_t)(pair_ & (NN - 1)) * (TT * CC);            \
        _Pragma("unroll")                                                     \
        for (int i_ = 0; i_ < 8; ++i_) {                                      \
          gload_lds16(in_ + (size_t)(tb + i_) * CC + lane * 4,                \
                      &sm->buf[(r) & 1][tb + i_][0]);                         \
        }                                                                     \
      } while (0)

    ISSUE_ROW(0);
    ISSUE_ROW(1);

    const float inv = 1.0f / TT;
    #pragma unroll
    for (int r = 0; r < RPB; ++r) {
      // gate: this row's 8 loads retired (8 newer belong to row r+1)
      if (r < RPB - 1) {
        asm volatile("s_waitcnt vmcnt(8)" ::: "memory");
      } else {
        asm volatile("s_waitcnt vmcnt(0)" ::: "memory");
      }
      float4 a0 = make_float4(0.f, 0.f, 0.f, 0.f);
      float4 a1 = make_float4(0.f, 0.f, 0.f, 0.f);
      #pragma unroll
      for (int i = 0; i < 8; i += 2) {
        float4 v = sm->buf[r & 1][tb + i][lane];
        float4 u = sm->buf[r & 1][tb + i + 1][lane];
        a0.x += v.x; a0.y += v.y; a0.z += v.z; a0.w += v.w;
        a1.x += u.x; a1.y += u.y; a1.z += u.z; a1.w += u.w;
      }
      float4 p = make_float4(a0.x + a1.x, a0.y + a1.y, a0.z + a1.z, a0.w + a1.w);
      if (w) sm->red[r & 1][w - 1][lane] = p;
      // raw barrier: LDS flushed, async-load queue NOT drained
      asm volatile("s_waitcnt lgkmcnt(0)" ::: "memory");
      __builtin_amdgcn_s_barrier();
      __builtin_amdgcn_sched_barrier(0);   // don't hoist red[] reads above
      if (r + 2 < RPB) ISSUE_ROW(r + 2);
      if (w == 0) {
        #pragma unroll
        for (int j = 0; j < 7; ++j) {
          float4 v = sm->red[r & 1][j][lane];
          p.x += v.x; p.y += v.y; p.z += v.z; p.w += v.w;
        }
        p.x *= inv; p.y *= inv; p.z *= inv; p.w *= inv;
        int pair = base + r;
        int n = pair & (NN - 1);
        float* xo = (pair >> 10) ? y : x;
        float* no = (pair >> 10) ? ny : nx;
        ((float4*)(xo + (size_t)n * CC))[lane] = p;
        float ssq = fmaf(p.x, p.x, fmaf(p.y, p.y, fmaf(p.z, p.z, p.w * p.w)));
        #pragma unroll
        for (int o = 32; o > 0; o >>= 1) ssq += __shfl_down(ssq, o, 64);
        if (lane == 0) no[n] = ssq;
      }
    }
    #undef ISSUE_ROW
  }

  __threadfence();   // device-scope: flush x/y/nx/ny past the XCD L2
  grid.sync();

  // ---------------- phase 2: pairwise-distance tile ----------------
  // block = tile (bi = blk>>4, bj = blk&15); 2 K-groups x 256 threads,
  // XOR-swizzled 128 KB LDS, 4x4 microtile — round-4 dist body verbatim.
  {
    DistSM* sm = (DistSM*)smraw;
    int blk = blockIdx.x;
    int bjx = blk & 15;
    int kg = tid >> 8;
    int s = tid & 255;
    int tx = s & 15, ty = s >> 4;
    int ti = (blk >> 4) * 64, tj = bjx * 64;

    float accx[4][4] = {};
    float accy[4][4] = {};

    const float4* gx = (const float4*)x;
    const float4* gy = (const float4*)y;

    __syncthreads();   // ensure all waves done with phase-1 LDS
    #pragma unroll
    for (int ph = 0; ph < 2; ++ph) {
      if (ph) __syncthreads();
      #pragma unroll
      for (int s2 = 0; s2 < 4; ++s2) {
        int f4 = tid + s2 * 512;
        int buf = f4 >> 10;
        int idx = f4 & 1023;
        int r = idx >> 4;
        int g = idx & 15;
        int pg = g ^ ((r >> 2) & 7);
        int col = (2 * ph + buf) * 16 + g;
        sm->tAX[buf][r][pg] = gx[(size_t)(ti + r) * 64 + col];
        sm->tAY[buf][r][pg] = gy[(size_t)(ti + r) * 64 + col];
        sm->tBX[buf][r][pg] = gx[(size_t)(tj + r) * 64 + col];
        sm->tBY[buf][r][pg] = gy[(size_t)(tj + r) * 64 + col];
      }
      __syncthreads();
      #pragma unroll
      for (int g = 0; g < 16; ++g) {
        float4 bxv[4], byv[4];
        int pgb = g ^ (tx & 7);
        #pragma unroll
        for (int q = 0; q < 4; ++q) {
          bxv[q] = sm->tBX[kg][4 * tx + q][pgb];
          byv[q] = sm->tBY[kg][4 * tx + q][pgb];
        }
        int pga = g ^ (ty & 7);
        #pragma unroll
        for (int p = 0; p < 4; ++p) {
          float4 ax = sm->tAX[kg][4 * ty + p][pga];
          float4 ay = sm->tAY[kg][4 * ty + p][pga];
          #pragma unroll
          for (int q = 0; q < 4; ++q) {
            accx[p][q] = fmaf(ax.w, bxv[q].w, fmaf(ax.z, bxv[q].z,
                         fmaf(ax.y, bxv[q].y, fmaf(ax.x, bxv[q].x, accx[p][q]))));
            accy[p][q] = fmaf(ay.w, byv[q].w, fmaf(ay.z, byv[q].z,
                         fmaf(ay.y, byv[q].y, fmaf(ay.x, byv[q].x, accy[p][q]))));
          }
        }
      }
    }

    // combine group-1 partial Gram into group-0
    __syncthreads();
    float4* cb4 = (float4*)&sm->tAX[0][0][0];
    if (kg == 1) {
      #pragma unroll
      for (int p = 0; p < 4; ++p) {
        cb4[p * 256 + s] = make_float4(accx[p][0], accx[p][1], accx[p][2], accx[p][3]);
        cb4[(4 + p) * 256 + s] = make_float4(accy[p][0], accy[p][1], accy[p][2], accy[p][3]);
      }
    }
    __syncthreads();

    float ab = 0.f, aa = 0.f, bb = 0.f;
    if (kg == 0) {
      #pragma unroll
      for (int p = 0; p < 4; ++p) {
        float4 v = cb4[p * 256 + s];
        accx[p][0] += v.x; accx[p][1] += v.y; accx[p][2] += v.z; accx[p][3] += v.w;
        float4 w2 = cb4[(4 + p) * 256 + s];
        accy[p][0] += w2.x; accy[p][1] += w2.y; accy[p][2] += w2.z; accy[p][3] += w2.w;
      }

      float nix[4], niy[4], njx[4], njy[4];
      #pragma unroll
      for (int p = 0; p < 4; ++p) { nix[p] = nx[ti + 4 * ty + p]; niy[p] = ny[ti + 4 * ty + p]; }
      #pragma unroll
      for (int q = 0; q < 4; ++q) { njx[q] = nx[tj + 4 * tx + q]; njy[q] = ny[tj + 4 * tx + q]; }

      #pragma unroll
      for (int p = 0; p < 4; ++p) {
        float rsx = 0.f, rsy = 0.f;
        #pragma unroll
        for (int q = 0; q < 4; ++q) {
          float dxv = sqrtf(fmaxf(nix[p] + njx[q] - 2.f * accx[p][q], 0.f) + 1e-12f);
          float dyv = sqrtf(fmaxf(niy[p] + njy[q] - 2.f * accy[p][q], 0.f) + 1e-12f);
          ab = fmaf(dxv, dyv, ab);
          aa = fmaf(dxv, dxv, aa);
          bb = fmaf(dyv, dyv, bb);
          rsx += dxv; rsy += dyv;
        }
        #pragma unroll
        for (int o = 8; o > 0; o >>= 1) {
          rsx += __shfl_down(rsx, o, 16);
          rsy += __shfl_down(rsy, o, 16);
        }
        if (tx == 0) {
          Rxp[bjx * NN + ti + 4 * ty + p] = rsx;
          Ryp[bjx * NN + ti + 4 * ty + p] = rsy;
        }
      }
    }

    #pragma unroll
    for (int o = 32; o > 0; o >>= 1) {
      ab += __shfl_down(ab, o, 64);
      aa += __shfl_down(aa, o, 64);
      bb += __shfl_down(bb, o, 64);
    }
    int wv = tid >> 6;
    if ((tid & 63) == 0) { sm->redp[0][wv] = ab; sm->redp[1][wv] = aa; sm->redp[2][wv] = bb; }
    __syncthreads();
    if (tid == 0) {
      float sab = 0.f, saa = 0.f, sbb = 0.f;
      #pragma unroll
      for (int w2 = 0; w2 < 8; ++w2) { sab += sm->redp[0][w2]; saa += sm->redp[1][w2]; sbb += sm->redp[2][w2]; }
      pab[blk] = sab; paa[blk] = saa; pbb[blk] = sbb;
    }
  }

  __threadfence();
  grid.sync();

  // ---------------- phase 3: finalize (block 0) ----------------
  if (blockIdx.x == 0) {
    double* t = (double*)smraw;   // t[8 vars][8 waves]
    const float4* rx4 = (const float4*)Rxp;
    const float4* ry4 = (const float4*)Ryp;
    float4 Rx = make_float4(0.f, 0.f, 0.f, 0.f);
    float4 Ry = make_float4(0.f, 0.f, 0.f, 0.f);
    double ab = 0.0, aa = 0.0, bb = 0.0;
    if (tid < 256) {
      #pragma unroll
      for (int b = 0; b < 16; ++b) {
        float4 v = rx4[b * 256 + tid];
        Rx.x += v.x; Rx.y += v.y; Rx.z += v.z; Rx.w += v.w;
        float4 w2 = ry4[b * 256 + tid];
        Ry.x += w2.x; Ry.y += w2.y; Ry.z += w2.z; Ry.w += w2.w;
      }
      ab = (double)pab[tid]; aa = (double)paa[tid]; bb = (double)pbb[tid];
    }
    double sx = (double)Rx.x + Rx.y + Rx.z + Rx.w;
    double sy = (double)Ry.x + Ry.y + Ry.z + Ry.w;
    double srr = (double)Rx.x * Ry.x + (double)Rx.y * Ry.y + (double)Rx.z * Ry.z + (double)Rx.w * Ry.w;
    double sxx = (double)Rx.x * Rx.x + (double)Rx.y * Rx.y + (double)Rx.z * Rx.z + (double)Rx.w * Rx.w;
    double syy = (double)Ry.x * Ry.x + (double)Ry.y * Ry.y + (double)Ry.z * Ry.z + (double)Ry.w * Ry.w;
    #pragma unroll
    for (int o = 32; o > 0; o >>= 1) {
      sx += __shfl_down(sx, o, 64);  sy += __shfl_down(sy, o, 64);
      srr += __shfl_down(srr, o, 64); sxx += __shfl_down(sxx, o, 64);
      syy += __shfl_down(syy, o, 64); ab += __shfl_down(ab, o, 64);
      aa += __shfl_down(aa, o, 64);  bb += __shfl_down(bb, o, 64);
    }
    int lane = tid & 63, w = tid >> 6;
    __syncthreads();   // smraw handoff from phase-2 layout
    if (lane == 0) {
      t[0 * 8 + w] = sx; t[1 * 8 + w] = sy; t[2 * 8 + w] = srr; t[3 * 8 + w] = sxx;
      t[4 * 8 + w] = syy; t[5 * 8 + w] = ab; t[6 * 8 + w] = aa; t[7 * 8 + w] = bb;
    }
    __syncthreads();
    if (tid == 0) {
      double v[8];
      #pragma unroll
      for (int k = 0; k < 8; ++k) {
        v[k] = 0.0;
        #pragma unroll
        for (int w2 = 0; w2 < 8; ++w2) v[k] += t[k * 8 + w2];
      }
      const double n = (double)NN, n2 = n * n;
      double AB = v[5] - (2.0 / n) * v[2] + v[0] * v[1] / n2;
      double AA = v[6] - (2.0 / n) * v[3] + v[0] * v[0] / n2;
      double BB = v[7] - (2.0 / n) * v[4] + v[1] * v[1] / n2;
      double xy = AB / n2, xx = AA / n2, yy = BB / n2;
      double r = xy / sqrt(xx * yy + 1e-9);
      out[0] = (float)(1.0 - r);
    }
  }
}

// =====================================================================
// Fallback path: the proven round-4 three-kernel pipeline, used only if
// hipLaunchCooperativeKernel is rejected (e.g. capture limitation).
// =====================================================================
__global__ __launch_bounds__(256) void mean_norm_kernel(
    const float* __restrict__ in0, const float* __restrict__ in1,
    float* __restrict__ x, float* __restrict__ y,
    float* __restrict__ nx, float* __restrict__ ny) {
  __shared__ float4 buf[2][TT][CC / 4];
  __shared__ float4 red[2][3][64];
  int tid = threadIdx.x;
  int w = tid >> 6;
  int lane = tid & 63;
  int tb = w * 16;
  int base = blockIdx.x * RPB;

  #define ISSUE_ROW(r)                                                        \
    do {                                                                      \
      int pair_ = base + (r);                                                 \
      const float* in_ = ((pair_ >> 10) ? in1 : in0) +                        \
                         (size_t)(pair_ & (NN - 1)) * (TT * CC);              \
      _Pragma("unroll")                                                       \
      for (int i_ = 0; i_ < 16; ++i_) {                                       \
        gload_lds16(in_ + (size_t)(tb + i_) * CC + lane * 4,                  \
                    &buf[(r) & 1][tb + i_][0]);                               \
      }                                                                       \
    } while (0)

  ISSUE_ROW(0);
  ISSUE_ROW(1);

  const float inv = 1.0f / TT;
  #pragma unroll
  for (int r = 0; r < RPB; ++r) {
    if (r < RPB - 1) {
      asm volatile("s_waitcnt vmcnt(16)" ::: "memory");
    } else {
      asm volatile("s_waitcnt vmcnt(0)" ::: "memory");
    }
    float4 a0 = make_float4(0.f, 0.f, 0.f, 0.f);
    float4 a1 = make_float4(0.f, 0.f, 0.f, 0.f);
    #pragma unroll
    for (int i = 0; i < 16; i += 2) {
      float4 v = buf[r & 1][tb + i][lane];
      float4 u = buf[r & 1][tb + i + 1][lane];
      a0.x += v.x; a0.y += v.y; a0.z += v.z; a0.w += v.w;
      a1.x += u.x; a1.y += u.y; a1.z += u.z; a1.w += u.w;
    }
    float4 p = make_float4(a0.x + a1.x, a0.y + a1.y, a0.z + a1.z, a0.w + a1.w);
    if (w) red[r & 1][w - 1][lane] = p;
    asm volatile("s_waitcnt lgkmcnt(0)" ::: "memory");
    __builtin_amdgcn_s_barrier();
    __builtin_amdgcn_sched_barrier(0);
    if (r + 2 < RPB) ISSUE_ROW(r + 2);
    if (w == 0) {
      #pragma unroll
      for (int j = 0; j < 3; ++j) {
        float4 v = red[r & 1][j][lane];
        p.x += v.x; p.y += v.y; p.z += v.z; p.w += v.w;
      }
      p.x *= inv; p.y *= inv; p.z *= inv; p.w *= inv;
      int pair = base + r;
      int n = pair & (NN - 1);
      float* xo = (pair >> 10) ? y : x;
      float* no = (pair >> 10) ? ny : nx;
      ((float4*)(xo + (size_t)n * CC))[lane] = p;
      float ssq = fmaf(p.x, p.x, fmaf(p.y, p.y, fmaf(p.z, p.z, p.w * p.w)));
      #pragma unroll
      for (int o = 32; o > 0; o >>= 1) ssq += __shfl_down(ssq, o, 64);
      if (lane == 0) no[n] = ssq;
    }
  }
  #undef ISSUE_ROW
}

__global__ __launch_bounds__(512) void dist_kernel(
    const float* __restrict__ x, const float* __restrict__ y,
    const float* __restrict__ nx, const float* __restrict__ ny,
    float* __restrict__ Rxp, float* __restrict__ Ryp,
    float* __restrict__ pab, float* __restrict__ paa, float* __restrict__ pbb) {
  __shared__ float4 tAX[2][64][16];
  __shared__ float4 tAY[2][64][16];
  __shared__ float4 tBX[2][64][16];
  __shared__ float4 tBY[2][64][16];
  __shared__ float redp[3][8];

  int tid = threadIdx.x;
  int kg = tid >> 8;
  int s = tid & 255;
  int tx = s & 15, ty = s >> 4;
  int ti = blockIdx.y * 64, tj = blockIdx.x * 64;

  float accx[4][4] = {};
  float accy[4][4] = {};

  const float4* gx = (const float4*)x;
  const float4* gy = (const float4*)y;

  #pragma unroll
  for (int ph = 0; ph < 2; ++ph) {
    if (ph) __syncthreads();
    #pragma unroll
    for (int s2 = 0; s2 < 4; ++s2) {
      int f4 = tid + s2 * 512;
      int buf = f4 >> 10;
      int idx = f4 & 1023;
      int r = idx >> 4;
      int g = idx & 15;
      int pg = g ^ ((r >> 2) & 7);
      int col = (2 * ph + buf) * 16 + g;
      tAX[buf][r][pg] = gx[(size_t)(ti + r) * 64 + col];
      tAY[buf][r][pg] = gy[(size_t)(ti + r) * 64 + col];
      tBX[buf][r][pg] = gx[(size_t)(tj + r) * 64 + col];
      tBY[buf][r][pg] = gy[(size_t)(tj + r) * 64 + col];
    }
    __syncthreads();
    #pragma unroll
    for (int g = 0; g < 16; ++g) {
      float4 bxv[4], byv[4];
      int pgb = g ^ (tx & 7);
      #pragma unroll
      for (int q = 0; q < 4; ++q) {
        bxv[q] = tBX[kg][4 * tx + q][pgb];
        byv[q] = tBY[kg][4 * tx + q][pgb];
      }
      int pga = g ^ (ty & 7);
      #pragma unroll
      for (int p = 0; p < 4; ++p) {
        float4 ax = tAX[kg][4 * ty + p][pga];
        float4 ay = tAY[kg][4 * ty + p][pga];
        #pragma unroll
        for (int q = 0; q < 4; ++q) {
          accx[p][q] = fmaf(ax.w, bxv[q].w, fmaf(ax.z, bxv[q].z,
                       fmaf(ax.y, bxv[q].y, fmaf(ax.x, bxv[q].x, accx[p][q]))));
          accy[p][q] = fmaf(ay.w, byv[q].w, fmaf(ay.z, byv[q].z,
                       fmaf(ay.y, byv[q].y, fmaf(ay.x, byv[q].x, accy[p][q]))));
        }
      }
    }
  }

  __syncthreads();
  float4* cb4 = (float4*)&tAX[0][0][0];
  if (kg == 1) {
    #pragma unroll
    for (int p = 0; p < 4; ++p) {
      cb4[p * 256 + s] = make_float4(accx[p][0], accx[p][1], accx[p][2], accx[p][3]);
      cb4[(4 + p) * 256 + s] = make_float4(accy[p][0], accy[p][1], accy[p][2], accy[p][3]);
    }
  }
  __syncthreads();

  float ab = 0.f, aa = 0.f, bb = 0.f;
  if (kg == 0) {
    #pragma unroll
    for (int p = 0; p < 4; ++p) {
      float4 v = cb4[p * 256 + s];
      accx[p][0] += v.x; accx[p][1] += v.y; accx[p][2] += v.z; accx[p][3] += v.w;
      float4 w = cb4[(4 + p) * 256 + s];
      accy[p][0] += w.x; accy[p][1] += w.y; accy[p][2] += w.z; accy[p][3] += w.w;
    }

    float nix[4], niy[4], njx[4], njy[4];
    #pragma unroll
    for (int p = 0; p < 4; ++p) { nix[p] = nx[ti + 4 * ty + p]; niy[p] = ny[ti + 4 * ty + p]; }
    #pragma unroll
    for (int q = 0; q < 4; ++q) { njx[q] = nx[tj + 4 * tx + q]; njy[q] = ny[tj + 4 * tx + q]; }

    #pragma unroll
    for (int p = 0; p < 4; ++p) {
      float rsx = 0.f, rsy = 0.f;
      #pragma unroll
      for (int q = 0; q < 4; ++q) {
        float dxv = sqrtf(fmaxf(nix[p] + njx[q] - 2.f * accx[p][q], 0.f) + 1e-12f);
        float dyv = sqrtf(fmaxf(niy[p] + njy[q] - 2.f * accy[p][q], 0.f) + 1e-12f);
        ab = fmaf(dxv, dyv, ab);
        aa = fmaf(dxv, dxv, aa);
        bb = fmaf(dyv, dyv, bb);
        rsx += dxv; rsy += dyv;
      }
      #pragma unroll
      for (int o = 8; o > 0; o >>= 1) {
        rsx += __shfl_down(rsx, o, 16);
        rsy += __shfl_down(rsy, o, 16);
      }
      if (tx == 0) {
        Rxp[blockIdx.x * NN + ti + 4 * ty + p] = rsx;
        Ryp[blockIdx.x * NN + ti + 4 * ty + p] = rsy;
      }
    }
  }

  #pragma unroll
  for (int o = 32; o > 0; o >>= 1) {
    ab += __shfl_down(ab, o, 64);
    aa += __shfl_down(aa, o, 64);
    bb += __shfl_down(bb, o, 64);
  }
  int wv = tid >> 6;
  if ((tid & 63) == 0) { redp[0][wv] = ab; redp[1][wv] = aa; redp[2][wv] = bb; }
  __syncthreads();
  if (tid == 0) {
    int blk = blockIdx.y * 16 + blockIdx.x;
    float sab = 0.f, saa = 0.f, sbb = 0.f;
    #pragma unroll
    for (int w = 0; w < 8; ++w) { sab += redp[0][w]; saa += redp[1][w]; sbb += redp[2][w]; }
    pab[blk] = sab; paa[blk] = saa; pbb[blk] = sbb;
  }
}

__global__ __launch_bounds__(256) void finalize_kernel(
    const float* __restrict__ Rxp, const float* __restrict__ Ryp,
    const float* __restrict__ pab, const float* __restrict__ paa,
    const float* __restrict__ pbb, float* __restrict__ out) {
  int tid = threadIdx.x;
  const float4* rx4 = (const float4*)Rxp;
  const float4* ry4 = (const float4*)Ryp;
  float4 Rx = make_float4(0.f, 0.f, 0.f, 0.f);
  float4 Ry = make_float4(0.f, 0.f, 0.f, 0.f);
  #pragma unroll
  for (int b = 0; b < 16; ++b) {
    float4 v = rx4[b * 256 + tid];
    Rx.x += v.x; Rx.y += v.y; Rx.z += v.z; Rx.w += v.w;
    float4 w = ry4[b * 256 + tid];
    Ry.x += w.x; Ry.y += w.y; Ry.z += w.z; Ry.w += w.w;
  }
  double sx = (double)Rx.x + Rx.y + Rx.z + Rx.w;
  double sy = (double)Ry.x + Ry.y + Ry.z + Ry.w;
  double srr = (double)Rx.x * Ry.x + (double)Rx.y * Ry.y + (double)Rx.z * Ry.z + (double)Rx.w * Ry.w;
  double sxx = (double)Rx.x * Rx.x + (double)Rx.y * Rx.y + (double)Rx.z * Rx.z + (double)Rx.w * Rx.w;
  double syy = (double)Ry.x * Ry.x + (double)Ry.y * Ry.y + (double)Ry.z * Ry.z + (double)Ry.w * Ry.w;
  double ab = (double)pab[tid];
  double aa = (double)paa[tid];
  double bb = (double)pbb[tid];
  #pragma unroll
  for (int o = 32; o > 0; o >>= 1) {
    sx += __shfl_down(sx, o, 64);  sy += __shfl_down(sy, o, 64);
    srr += __shfl_down(srr, o, 64); sxx += __shfl_down(sxx, o, 64);
    syy += __shfl_down(syy, o, 64); ab += __shfl_down(ab, o, 64);
    aa += __shfl_down(aa, o, 64);  bb += __shfl_down(bb, o, 64);
  }
  __shared__ double t[8][4];
  int lane = tid & 63, w = tid >> 6;
  if (lane == 0) {
    t[0][w] = sx; t[1][w] = sy; t[2][w] = srr; t[3][w] = sxx;
    t[4][w] = syy; t[5][w] = ab; t[6][w] = aa; t[7][w] = bb;
  }
  __syncthreads();
  if (tid == 0) {
    sx  = t[0][0] + t[0][1] + t[0][2] + t[0][3];
    sy  = t[1][0] + t[1][1] + t[1][2] + t[1][3];
    srr = t[2][0] + t[2][1] + t[2][2] + t[2][3];
    sxx = t[3][0] + t[3][1] + t[3][2] + t[3][3];
    syy = t[4][0] + t[4][1] + t[4][2] + t[4][3];
    ab  = t[5][0] + t[5][1] + t[5][2] + t[5][3];
    aa  = t[6][0] + t[6][1] + t[6][2] + t[6][3];
    bb  = t[7][0] + t[7][1] + t[7][2] + t[7][3];
    const double n = (double)NN, n2 = n * n;
    double AB = ab - (2.0 / n) * srr + sx * sy / n2;
    double AA = aa - (2.0 / n) * sxx + sx * sx / n2;
    double BB = bb - (2.0 / n) * syy + sy * sy / n2;
    double xy = AB / n2, xx = AA / n2, yy = BB / n2;
    double r = xy / sqrt(xx * yy + 1e-9);
    out[0] = (float)(1.0 - r);
  }
}

extern "C" void kernel_launch(void* const* d_in, const int* in_sizes, int n_in,
                              void* d_out, int out_size, void* d_ws, size_t ws_size,
                              hipStream_t stream) {
  const float* in0 = (const float*)d_in[0];   // output_1 (N,T,C) fp32
  const float* in1 = (const float*)d_in[1];   // feature  (N,T,C) fp32

  char* ws = (char*)d_ws;
  float* x   = (float*)(ws);                          // 1 MB
  float* y   = (float*)(ws + (1u << 20));             // 1 MB
  float* nx  = (float*)(ws + (2u << 20));             // 4 KB
  float* ny  = (float*)(ws + (2u << 20) + 4096);      // 4 KB
  float* Rxp = (float*)(ws + (2u << 20) + 8192);      // 64 KB (16x1024)
  float* Ryp = (float*)(ws + (2u << 20) + 8192 + 65536);        // 64 KB
  float* pab = (float*)(ws + (2u << 20) + 8192 + 2 * 65536);    // 1 KB
  float* paa = (float*)(ws + (2u << 20) + 8192 + 2 * 65536 + 1024);
  float* pbb = (float*)(ws + (2u << 20) + 8192 + 2 * 65536 + 2048);
  float* outp = (float*)d_out;

  void* args[] = {&in0, &in1, &x, &y, &nx, &ny, &Rxp, &Ryp, &pab, &paa, &pbb, &outp};
  hipError_t err = hipLaunchCooperativeKernel(
      reinterpret_cast<void*>(fused_kernel), dim3(256), dim3(512), args, 0, stream);
  if (err != hipSuccess) {
    // fallback: proven 3-kernel pipeline
    mean_norm_kernel<<<2 * NN / RPB, 256, 0, stream>>>(in0, in1, x, y, nx, ny);
    dist_kernel<<<dim3(16, 16), 512, 0, stream>>>(x, y, nx, ny, Rxp, Ryp, pab, paa, pbb);
    finalize_kernel<<<1, 256, 0, stream>>>(Rxp, Ryp, pab, paa, pbb, outp);
  }
}

// Round 6
// 193.810 us; speedup vs baseline: 1.6586x; 1.6586x over previous
//
#include <hip/hip_runtime.h>
#include <math.h>

#define NN 1024
#define CC 256
#define TT 64

// async global->LDS, 16B per lane. LDS dest is wave-uniform base + lane*16;
// global src is per-lane. Zero VGPR cost per outstanding load -> the
// compiler cannot collapse the pipeline (rounds 1-2 lesson: VGPR-staged
// double-buffers get rescheduled down to ~4 loads in flight).
#define AS1 __attribute__((address_space(1)))
#define AS3 __attribute__((address_space(3)))
static __device__ __forceinline__ void gload_lds16(const float* g, float4* l) {
  __builtin_amdgcn_global_load_lds((const AS1 void*)g, (AS3 void*)l, 16, 0, 0);
}

// ---------------- kernel 1: fused time-mean + row norm ----------------
// Round-3 proven version (best total 171.6us). One block per (tensor,row):
// 2048 blocks x 256 threads. Wave w stages its 16 time-steps of the 64KB
// row into LDS via 16 back-to-back global_load_lds_dwordx4; consumption
// gated by counted s_waitcnt vmcnt(12/8/4/0). Measured 42-46us = ~2.9TB/s
// effective read; three structurally different variants (rounds 1/3/4) all
// hit the same wall -> treated as this op's empirical read ceiling.
__global__ __launch_bounds__(256) void mean_norm_kernel(
    const float* __restrict__ in0, const float* __restrict__ in1,
    float* __restrict__ x, float* __restrict__ y,
    float* __restrict__ nx, float* __restrict__ ny) {
  __shared__ float4 buf[TT][CC / 4];   // 64 KB, [t][float4-group]
  __shared__ float4 red[3][64];
  int b = blockIdx.x;
  int m = b >> 10;
  int n = b & (NN - 1);
  const float* in = (m ? in1 : in0) + (size_t)n * (TT * CC);
  float* xo = m ? y : x;
  float* no = m ? ny : nx;
  int tid = threadIdx.x;
  int w = tid >> 6;          // wave id = time-quarter
  int lane = tid & 63;
  int tb = w * 16;           // this wave's first time-step

  #pragma unroll
  for (int i = 0; i < 16; ++i) {
    gload_lds16(in + (size_t)(tb + i) * CC + lane * 4, &buf[tb + i][0]);
  }

  float4 a0 = make_float4(0.f, 0.f, 0.f, 0.f);
  float4 a1 = make_float4(0.f, 0.f, 0.f, 0.f);

  asm volatile("s_waitcnt vmcnt(12)" ::: "memory");
  #pragma unroll
  for (int i = 0; i < 4; i += 2) {
    float4 v = buf[tb + i][lane];
    float4 u = buf[tb + i + 1][lane];
    a0.x += v.x; a0.y += v.y; a0.z += v.z; a0.w += v.w;
    a1.x += u.x; a1.y += u.y; a1.z += u.z; a1.w += u.w;
  }
  asm volatile("s_waitcnt vmcnt(8)" ::: "memory");
  #pragma unroll
  for (int i = 4; i < 8; i += 2) {
    float4 v = buf[tb + i][lane];
    float4 u = buf[tb + i + 1][lane];
    a0.x += v.x; a0.y += v.y; a0.z += v.z; a0.w += v.w;
    a1.x += u.x; a1.y += u.y; a1.z += u.z; a1.w += u.w;
  }
  asm volatile("s_waitcnt vmcnt(4)" ::: "memory");
  #pragma unroll
  for (int i = 8; i < 12; i += 2) {
    float4 v = buf[tb + i][lane];
    float4 u = buf[tb + i + 1][lane];
    a0.x += v.x; a0.y += v.y; a0.z += v.z; a0.w += v.w;
    a1.x += u.x; a1.y += u.y; a1.z += u.z; a1.w += u.w;
  }
  asm volatile("s_waitcnt vmcnt(0)" ::: "memory");
  #pragma unroll
  for (int i = 12; i < 16; i += 2) {
    float4 v = buf[tb + i][lane];
    float4 u = buf[tb + i + 1][lane];
    a0.x += v.x; a0.y += v.y; a0.z += v.z; a0.w += v.w;
    a1.x += u.x; a1.y += u.y; a1.z += u.z; a1.w += u.w;
  }

  float4 p = make_float4(a0.x + a1.x, a0.y + a1.y, a0.z + a1.z, a0.w + a1.w);
  if (w) red[w - 1][lane] = p;
  __syncthreads();
  if (w == 0) {
    #pragma unroll
    for (int j = 0; j < 3; ++j) {
      float4 v = red[j][lane];
      p.x += v.x; p.y += v.y; p.z += v.z; p.w += v.w;
    }
    const float inv = 1.0f / TT;
    p.x *= inv; p.y *= inv; p.z *= inv; p.w *= inv;
    ((float4*)(xo + (size_t)n * CC))[lane] = p;
    float ssq = fmaf(p.x, p.x, fmaf(p.y, p.y, fmaf(p.z, p.z, p.w * p.w)));
    #pragma unroll
    for (int o = 32; o > 0; o >>= 1) ssq += __shfl_down(ssq, o, 64);
    if (lane == 0) no[n] = ssq;
  }
}

// ---------------- kernel 2: fused pairwise-distance + reductions ----------------
// Grid (16,16): 64x64 tile, 1024 threads = 4 K-groups x 256 (was 2x256).
// Doubles wave-level latency hiding (4 waves/SIMD) at CONSTANT LDS traffic
// and fma:read ratio. LDS: tb[array AX/AY/BX/BY][chunk=group][64 rows][8 f4]
// = 128 KB; phase ph stages group kg's f4-columns kg*16 + ph*8 + (0..7).
// Additive slot swizzle (g + (r>>2)) & 7:
//   B-reads: 16 rows (4tx+q) -> slot (g+tx)&7 -> 8 slots x 2 rows  (free)
//   A-reads: 4 rows (4ty+p)  -> slot (g+ty)&7 -> 4 slots x 1 + bcast (free)
//   staging writes: 64 lanes -> 8 slots x 8 even                   (min)
// Groups 1-3 combine into group 0 via reused-LDS scratch; group 0 runs the
// proven epilogue (d=sqrt(ni+nj-2g), row partials, block product partials).
__global__ __launch_bounds__(1024) void dist_kernel(
    const float* __restrict__ x, const float* __restrict__ y,
    const float* __restrict__ nx, const float* __restrict__ ny,
    float* __restrict__ Rxp, float* __restrict__ Ryp,
    float* __restrict__ pab, float* __restrict__ paa, float* __restrict__ pbb) {
  __shared__ float4 tb[4][4][64][8];   // [AX,AY,BX,BY][chunk][row][slot] 128 KB
  __shared__ float redp[3][16];

  int tid = threadIdx.x;
  int kg = tid >> 8;             // K-group 0..3
  int s = tid & 255;             // id within group
  int tx = s & 15, ty = s >> 4;
  int ti = blockIdx.y * 64, tj = blockIdx.x * 64;

  float accx[4][4] = {};
  float accy[4][4] = {};

  const float4* gx = (const float4*)x;   // [row][64] float4 groups
  const float4* gy = (const float4*)y;

  // one staging store: S2 selects array (S2>>1) and row-half (S2&1)
  #define STG(S2, SRCP, ROW0)                                                 \
    do {                                                                      \
      int r_ = ((S2) & 1) * 32 + (tid >> 5);                                  \
      int w32_ = tid & 31;                                                    \
      int c_ = w32_ >> 3;                                                     \
      int g_ = w32_ & 7;                                                      \
      tb[(S2) >> 1][c_][r_][(g_ + (r_ >> 2)) & 7] =                           \
          SRCP[(size_t)((ROW0) + r_) * 64 + c_ * 16 + ph * 8 + g_];           \
    } while (0)

  #pragma unroll
  for (int ph = 0; ph < 2; ++ph) {
    if (ph) __syncthreads();           // protect LDS from previous compute
    STG(0, gx, ti); STG(1, gx, ti);    // AX rows 0-31, 32-63
    STG(2, gy, ti); STG(3, gy, ti);    // AY
    STG(4, gx, tj); STG(5, gx, tj);    // BX
    STG(6, gy, tj); STG(7, gy, tj);    // BY
    __syncthreads();
    #pragma unroll
    for (int g = 0; g < 8; ++g) {      // group kg computes on chunk kg
      float4 bxv[4], byv[4];
      int slb = (g + tx) & 7;
      #pragma unroll
      for (int q = 0; q < 4; ++q) {
        bxv[q] = tb[2][kg][4 * tx + q][slb];
        byv[q] = tb[3][kg][4 * tx + q][slb];
      }
      int sla = (g + ty) & 7;
      #pragma unroll
      for (int p = 0; p < 4; ++p) {
        float4 ax = tb[0][kg][4 * ty + p][sla];
        float4 ay = tb[1][kg][4 * ty + p][sla];
        #pragma unroll
        for (int q = 0; q < 4; ++q) {
          accx[p][q] = fmaf(ax.w, bxv[q].w, fmaf(ax.z, bxv[q].z,
                       fmaf(ax.y, bxv[q].y, fmaf(ax.x, bxv[q].x, accx[p][q]))));
          accy[p][q] = fmaf(ay.w, byv[q].w, fmaf(ay.z, byv[q].z,
                       fmaf(ay.y, byv[q].y, fmaf(ay.x, byv[q].x, accy[p][q]))));
        }
      }
    }
  }
  #undef STG

  // ---- combine groups 1-3 into group 0 (conflict-free, reused LDS) ----
  __syncthreads();
  float4* cb4 = &tb[0][0][0][0];       // 6144 f4 used of 8192
  if (kg > 0) {
    #pragma unroll
    for (int p = 0; p < 4; ++p) {
      cb4[((kg - 1) * 8 + p) * 256 + s] =
          make_float4(accx[p][0], accx[p][1], accx[p][2], accx[p][3]);
      cb4[((kg - 1) * 8 + 4 + p) * 256 + s] =
          make_float4(accy[p][0], accy[p][1], accy[p][2], accy[p][3]);
    }
  }
  __syncthreads();

  float ab = 0.f, aa = 0.f, bb = 0.f;
  if (kg == 0) {
    #pragma unroll
    for (int j = 0; j < 3; ++j) {
      #pragma unroll
      for (int p = 0; p < 4; ++p) {
        float4 v = cb4[(j * 8 + p) * 256 + s];
        accx[p][0] += v.x; accx[p][1] += v.y; accx[p][2] += v.z; accx[p][3] += v.w;
        float4 w2 = cb4[(j * 8 + 4 + p) * 256 + s];
        accy[p][0] += w2.x; accy[p][1] += w2.y; accy[p][2] += w2.z; accy[p][3] += w2.w;
      }
    }

    // epilogue: d = sqrt(max(ni+nj-2g,0)+1e-12); accumulate sums
    float nix[4], niy[4], njx[4], njy[4];
    #pragma unroll
    for (int p = 0; p < 4; ++p) { nix[p] = nx[ti + 4 * ty + p]; niy[p] = ny[ti + 4 * ty + p]; }
    #pragma unroll
    for (int q = 0; q < 4; ++q) { njx[q] = nx[tj + 4 * tx + q]; njy[q] = ny[tj + 4 * tx + q]; }

    #pragma unroll
    for (int p = 0; p < 4; ++p) {
      float rsx = 0.f, rsy = 0.f;
      #pragma unroll
      for (int q = 0; q < 4; ++q) {
        float dxv = sqrtf(fmaxf(nix[p] + njx[q] - 2.f * accx[p][q], 0.f) + 1e-12f);
        float dyv = sqrtf(fmaxf(niy[p] + njy[q] - 2.f * accy[p][q], 0.f) + 1e-12f);
        ab = fmaf(dxv, dyv, ab);
        aa = fmaf(dxv, dxv, aa);
        bb = fmaf(dyv, dyv, bb);
        rsx += dxv; rsy += dyv;
      }
      // reduce row partial over the 16 tx-lanes of this ty-group
      #pragma unroll
      for (int o = 8; o > 0; o >>= 1) {
        rsx += __shfl_down(rsx, o, 16);
        rsy += __shfl_down(rsy, o, 16);
      }
      if (tx == 0) {
        Rxp[blockIdx.x * NN + ti + 4 * ty + p] = rsx;
        Ryp[blockIdx.x * NN + ti + 4 * ty + p] = rsy;
      }
    }
  }

  // block-level product partials over all 16 waves (groups 1-3 carry zeros)
  #pragma unroll
  for (int o = 32; o > 0; o >>= 1) {
    ab += __shfl_down(ab, o, 64);
    aa += __shfl_down(aa, o, 64);
    bb += __shfl_down(bb, o, 64);
  }
  int wv = tid >> 6;
  if ((tid & 63) == 0) { redp[0][wv] = ab; redp[1][wv] = aa; redp[2][wv] = bb; }
  __syncthreads();
  if (tid == 0) {
    int blk = blockIdx.y * 16 + blockIdx.x;
    float sab = 0.f, saa = 0.f, sbb = 0.f;
    #pragma unroll
    for (int w = 0; w < 16; ++w) { sab += redp[0][w]; saa += redp[1][w]; sbb += redp[2][w]; }
    pab[blk] = sab; paa[blk] = saa; pbb[blk] = sbb;
  }
}

// ---------------- kernel 3: finalize ----------------
// <A,B> = S(DxDy) - (2/n) S(Rx.Ry) + Sx.Sy/n^2  (H idempotent, D symmetric)
__global__ __launch_bounds__(256) void finalize_kernel(
    const float* __restrict__ Rxp, const float* __restrict__ Ryp,
    const float* __restrict__ pab, const float* __restrict__ paa,
    const float* __restrict__ pbb, float* __restrict__ out) {
  int tid = threadIdx.x;
  const float4* rx4 = (const float4*)Rxp;
  const float4* ry4 = (const float4*)Ryp;
  float4 Rx = make_float4(0.f, 0.f, 0.f, 0.f);
  float4 Ry = make_float4(0.f, 0.f, 0.f, 0.f);
  #pragma unroll
  for (int b = 0; b < 16; ++b) {
    float4 v = rx4[b * 256 + tid];
    Rx.x += v.x; Rx.y += v.y; Rx.z += v.z; Rx.w += v.w;
    float4 w = ry4[b * 256 + tid];
    Ry.x += w.x; Ry.y += w.y; Ry.z += w.z; Ry.w += w.w;
  }
  double sx = (double)Rx.x + Rx.y + Rx.z + Rx.w;
  double sy = (double)Ry.x + Ry.y + Ry.z + Ry.w;
  double srr = (double)Rx.x * Ry.x + (double)Rx.y * Ry.y + (double)Rx.z * Ry.z + (double)Rx.w * Ry.w;
  double sxx = (double)Rx.x * Rx.x + (double)Rx.y * Rx.y + (double)Rx.z * Rx.z + (double)Rx.w * Rx.w;
  double syy = (double)Ry.x * Ry.x + (double)Ry.y * Ry.y + (double)Ry.z * Ry.z + (double)Ry.w * Ry.w;
  double ab = (double)pab[tid];   // 256 partials, 256 threads
  double aa = (double)paa[tid];
  double bb = (double)pbb[tid];
  #pragma unroll
  for (int o = 32; o > 0; o >>= 1) {
    sx += __shfl_down(sx, o, 64);  sy += __shfl_down(sy, o, 64);
    srr += __shfl_down(srr, o, 64); sxx += __shfl_down(sxx, o, 64);
    syy += __shfl_down(syy, o, 64); ab += __shfl_down(ab, o, 64);
    aa += __shfl_down(aa, o, 64);  bb += __shfl_down(bb, o, 64);
  }
  __shared__ double t[8][4];
  int lane = tid & 63, w = tid >> 6;
  if (lane == 0) {
    t[0][w] = sx; t[1][w] = sy; t[2][w] = srr; t[3][w] = sxx;
    t[4][w] = syy; t[5][w] = ab; t[6][w] = aa; t[7][w] = bb;
  }
  __syncthreads();
  if (tid == 0) {
    sx  = t[0][0] + t[0][1] + t[0][2] + t[0][3];
    sy  = t[1][0] + t[1][1] + t[1][2] + t[1][3];
    srr = t[2][0] + t[2][1] + t[2][2] + t[2][3];
    sxx = t[3][0] + t[3][1] + t[3][2] + t[3][3];
    syy = t[4][0] + t[4][1] + t[4][2] + t[4][3];
    ab  = t[5][0] + t[5][1] + t[5][2] + t[5][3];
    aa  = t[6][0] + t[6][1] + t[6][2] + t[6][3];
    bb  = t[7][0] + t[7][1] + t[7][2] + t[7][3];
    const double n = (double)NN, n2 = n * n;
    double AB = ab - (2.0 / n) * srr + sx * sy / n2;
    double AA = aa - (2.0 / n) * sxx + sx * sx / n2;
    double BB = bb - (2.0 / n) * syy + sy * sy / n2;
    double xy = AB / n2, xx = AA / n2, yy = BB / n2;
    double r = xy / sqrt(xx * yy + 1e-9);
    out[0] = (float)(1.0 - r);
  }
}

extern "C" void kernel_launch(void* const* d_in, const int* in_sizes, int n_in,
                              void* d_out, int out_size, void* d_ws, size_t ws_size,
                              hipStream_t stream) {
  const float* in0 = (const float*)d_in[0];   // output_1 (N,T,C) fp32
  const float* in1 = (const float*)d_in[1];   // feature  (N,T,C) fp32

  char* ws = (char*)d_ws;
  float* x   = (float*)(ws);                          // 1 MB
  float* y   = (float*)(ws + (1u << 20));             // 1 MB
  float* nx  = (float*)(ws + (2u << 20));             // 4 KB
  float* ny  = (float*)(ws + (2u << 20) + 4096);      // 4 KB
  float* Rxp = (float*)(ws + (2u << 20) + 8192);      // 64 KB (16x1024)
  float* Ryp = (float*)(ws + (2u << 20) + 8192 + 65536);        // 64 KB
  float* pab = (float*)(ws + (2u << 20) + 8192 + 2 * 65536);    // 1 KB
  float* paa = (float*)(ws + (2u << 20) + 8192 + 2 * 65536 + 1024);
  float* pbb = (float*)(ws + (2u << 20) + 8192 + 2 * 65536 + 2048);

  mean_norm_kernel<<<2 * NN, 256, 0, stream>>>(in0, in1, x, y, nx, ny);
  dist_kernel<<<dim3(16, 16), 1024, 0, stream>>>(x, y, nx, ny, Rxp, Ryp, pab, paa, pbb);
  finalize_kernel<<<1, 256, 0, stream>>>(Rxp, Ryp, pab, paa, pbb, (float*)d_out);
}

// Round 7
// 167.236 us; speedup vs baseline: 1.9221x; 1.1589x over previous
//
#include <hip/hip_runtime.h>
#include <math.h>

#define NN 1024
#define CC 256
#define TT 64

typedef float __attribute__((ext_vector_type(4))) f32x4;

// ---------------- kernel 1: fused time-mean + row norm ----------------
// Block per (tensor,row): 2048 blocks x 256 threads; wave w sums t-steps
// [16w,16w+16), lane owns float4-group lane. NON-TEMPORAL loads: 5 prior
// structures (shallow-VGPR, wave-per-row, 16-deep async-LDS, persistent)
// all hit ~2.9 TB/s with 60-128KB/CU in flight (only ~9KB needed for
// latency cover) -> throttle is the mixed L3-hit/HBM-miss return path
// (FETCH_SIZE constant 67MB = half the input L3-resident). NT loads stop
// L3 retention -> subsequent iterations stream pure HBM (m13 regime,
// 6.29 TB/s known-good). Falsifier: FETCH jumps to ~131K KB but dur
// stays ~45us -> request-path throttle, mean is ceiling'd.
__global__ __launch_bounds__(256) void mean_norm_kernel(
    const float* __restrict__ in0, const float* __restrict__ in1,
    float* __restrict__ x, float* __restrict__ y,
    float* __restrict__ nx, float* __restrict__ ny) {
  __shared__ f32x4 red[3][64];
  int b = blockIdx.x;
  int m = b >> 10;
  int n = b & (NN - 1);
  const f32x4* src = (const f32x4*)((m ? in1 : in0) + (size_t)n * (TT * CC));
  float* xo = m ? y : x;
  float* no = m ? ny : nx;
  int tid = threadIdx.x;
  int w = tid >> 6;            // wave id = time-quarter
  int lane = tid & 63;
  const f32x4* p0 = src + (size_t)(w * 16) * (CC / 4) + lane;

  f32x4 a0 = (f32x4)0.f;
  f32x4 a1 = (f32x4)0.f;
  #pragma unroll
  for (int i = 0; i < 16; i += 2) {
    a0 += __builtin_nontemporal_load(p0 + (size_t)i * (CC / 4));
    a1 += __builtin_nontemporal_load(p0 + (size_t)(i + 1) * (CC / 4));
  }
  f32x4 s = a0 + a1;
  if (w) red[w - 1][lane] = s;
  __syncthreads();
  if (w == 0) {
    #pragma unroll
    for (int j = 0; j < 3; ++j) s += red[j][lane];
    s *= (1.0f / TT);
    ((f32x4*)(xo + (size_t)n * CC))[lane] = s;
    float ssq = fmaf(s.x, s.x, fmaf(s.y, s.y, fmaf(s.z, s.z, s.w * s.w)));
    #pragma unroll
    for (int o = 32; o > 0; o >>= 1) ssq += __shfl_down(ssq, o, 64);
    if (lane == 0) no[n] = ssq;
  }
}

// ---------------- kernel 2: fused pairwise-distance + reductions ----------------
// PROVEN round-1/2/3 version (implied ~40us; the 1024-thread split-4 of
// round 6 regressed to ~57us -> reverted). Grid (16,16): 64x64 tile,
// 512 threads = 2 K-groups x 256; both chunk buffers in LDS (128 KB),
// XOR-swizzled, 4x4 microtile; group-1 Gram combined into group-0 via
// reused-LDS scratch; group 0 runs the epilogue.
__global__ __launch_bounds__(512) void dist_kernel(
    const float* __restrict__ x, const float* __restrict__ y,
    const float* __restrict__ nx, const float* __restrict__ ny,
    float* __restrict__ Rxp, float* __restrict__ Ryp,
    float* __restrict__ pab, float* __restrict__ paa, float* __restrict__ pbb) {
  __shared__ float4 tAX[2][64][16];
  __shared__ float4 tAY[2][64][16];
  __shared__ float4 tBX[2][64][16];
  __shared__ float4 tBY[2][64][16];
  __shared__ float redp[3][8];

  int tid = threadIdx.x;
  int kg = tid >> 8;             // K-group: waves 0-3 -> 0, waves 4-7 -> 1
  int s = tid & 255;             // id within group
  int tx = s & 15, ty = s >> 4;
  int ti = blockIdx.y * 64, tj = blockIdx.x * 64;

  float accx[4][4] = {};
  float accy[4][4] = {};

  const float4* gx = (const float4*)x;   // [row][64] float4 groups
  const float4* gy = (const float4*)y;

  #pragma unroll
  for (int ph = 0; ph < 2; ++ph) {       // phase ph stages chunks 2ph, 2ph+1
    if (ph) __syncthreads();             // protect LDS from previous compute
    #pragma unroll
    for (int s2 = 0; s2 < 4; ++s2) {
      int f4 = tid + s2 * 512;           // 0..2047
      int buf = f4 >> 10;                // which chunk buffer
      int idx = f4 & 1023;
      int r = idx >> 4;                  // 0..63
      int g = idx & 15;
      int pg = g ^ ((r >> 2) & 7);
      int col = (2 * ph + buf) * 16 + g; // global float4-group column
      tAX[buf][r][pg] = gx[(size_t)(ti + r) * 64 + col];
      tAY[buf][r][pg] = gy[(size_t)(ti + r) * 64 + col];
      tBX[buf][r][pg] = gx[(size_t)(tj + r) * 64 + col];
      tBY[buf][r][pg] = gy[(size_t)(tj + r) * 64 + col];
    }
    __syncthreads();
    #pragma unroll
    for (int g = 0; g < 16; ++g) {       // group kg computes on its own buffer
      float4 bxv[4], byv[4];
      int pgb = g ^ (tx & 7);
      #pragma unroll
      for (int q = 0; q < 4; ++q) {
        bxv[q] = tBX[kg][4 * tx + q][pgb];
        byv[q] = tBY[kg][4 * tx + q][pgb];
      }
      int pga = g ^ (ty & 7);
      #pragma unroll
      for (int p = 0; p < 4; ++p) {
        float4 ax = tAX[kg][4 * ty + p][pga];
        float4 ay = tAY[kg][4 * ty + p][pga];
        #pragma unroll
        for (int q = 0; q < 4; ++q) {
          accx[p][q] = fmaf(ax.w, bxv[q].w, fmaf(ax.z, bxv[q].z,
                       fmaf(ax.y, bxv[q].y, fmaf(ax.x, bxv[q].x, accx[p][q]))));
          accy[p][q] = fmaf(ay.w, byv[q].w, fmaf(ay.z, byv[q].z,
                       fmaf(ay.y, byv[q].y, fmaf(ay.x, byv[q].x, accy[p][q]))));
        }
      }
    }
  }

  // ---- combine group-1 partial Gram into group-0 (conflict-free layout) ----
  __syncthreads();
  float4* cb4 = (float4*)&tAX[0][0][0];  // 32 KB scratch = 8 slots x 256 thr
  if (kg == 1) {
    #pragma unroll
    for (int p = 0; p < 4; ++p) {
      cb4[p * 256 + s] = make_float4(accx[p][0], accx[p][1], accx[p][2], accx[p][3]);
      cb4[(4 + p) * 256 + s] = make_float4(accy[p][0], accy[p][1], accy[p][2], accy[p][3]);
    }
  }
  __syncthreads();

  float ab = 0.f, aa = 0.f, bb = 0.f;
  if (kg == 0) {
    #pragma unroll
    for (int p = 0; p < 4; ++p) {
      float4 v = cb4[p * 256 + s];
      accx[p][0] += v.x; accx[p][1] += v.y; accx[p][2] += v.z; accx[p][3] += v.w;
      float4 w = cb4[(4 + p) * 256 + s];
      accy[p][0] += w.x; accy[p][1] += w.y; accy[p][2] += w.z; accy[p][3] += w.w;
    }

    // epilogue: d = sqrt(max(ni+nj-2g,0)+1e-12); accumulate sums
    float nix[4], niy[4], njx[4], njy[4];
    #pragma unroll
    for (int p = 0; p < 4; ++p) { nix[p] = nx[ti + 4 * ty + p]; niy[p] = ny[ti + 4 * ty + p]; }
    #pragma unroll
    for (int q = 0; q < 4; ++q) { njx[q] = nx[tj + 4 * tx + q]; njy[q] = ny[tj + 4 * tx + q]; }

    #pragma unroll
    for (int p = 0; p < 4; ++p) {
      float rsx = 0.f, rsy = 0.f;
      #pragma unroll
      for (int q = 0; q < 4; ++q) {
        float dxv = sqrtf(fmaxf(nix[p] + njx[q] - 2.f * accx[p][q], 0.f) + 1e-12f);
        float dyv = sqrtf(fmaxf(niy[p] + njy[q] - 2.f * accy[p][q], 0.f) + 1e-12f);
        ab = fmaf(dxv, dyv, ab);
        aa = fmaf(dxv, dxv, aa);
        bb = fmaf(dyv, dyv, bb);
        rsx += dxv; rsy += dyv;
      }
      // reduce row partial over the 16 tx-lanes of this ty-group
      #pragma unroll
      for (int o = 8; o > 0; o >>= 1) {
        rsx += __shfl_down(rsx, o, 16);
        rsy += __shfl_down(rsy, o, 16);
      }
      if (tx == 0) {
        Rxp[blockIdx.x * NN + ti + 4 * ty + p] = rsx;
        Ryp[blockIdx.x * NN + ti + 4 * ty + p] = rsy;
      }
    }
  }

  // block-level product partials over all 8 waves (group-1 waves carry zeros)
  #pragma unroll
  for (int o = 32; o > 0; o >>= 1) {
    ab += __shfl_down(ab, o, 64);
    aa += __shfl_down(aa, o, 64);
    bb += __shfl_down(bb, o, 64);
  }
  int wv = tid >> 6;
  if ((tid & 63) == 0) { redp[0][wv] = ab; redp[1][wv] = aa; redp[2][wv] = bb; }
  __syncthreads();
  if (tid == 0) {
    int blk = blockIdx.y * 16 + blockIdx.x;
    float sab = 0.f, saa = 0.f, sbb = 0.f;
    #pragma unroll
    for (int w = 0; w < 8; ++w) { sab += redp[0][w]; saa += redp[1][w]; sbb += redp[2][w]; }
    pab[blk] = sab; paa[blk] = saa; pbb[blk] = sbb;
  }
}

// ---------------- kernel 3: finalize ----------------
// <A,B> = S(DxDy) - (2/n) S(Rx.Ry) + Sx.Sy/n^2  (H idempotent, D symmetric)
__global__ __launch_bounds__(256) void finalize_kernel(
    const float* __restrict__ Rxp, const float* __restrict__ Ryp,
    const float* __restrict__ pab, const float* __restrict__ paa,
    const float* __restrict__ pbb, float* __restrict__ out) {
  int tid = threadIdx.x;
  const float4* rx4 = (const float4*)Rxp;
  const float4* ry4 = (const float4*)Ryp;
  float4 Rx = make_float4(0.f, 0.f, 0.f, 0.f);
  float4 Ry = make_float4(0.f, 0.f, 0.f, 0.f);
  #pragma unroll
  for (int b = 0; b < 16; ++b) {
    float4 v = rx4[b * 256 + tid];
    Rx.x += v.x; Rx.y += v.y; Rx.z += v.z; Rx.w += v.w;
    float4 w = ry4[b * 256 + tid];
    Ry.x += w.x; Ry.y += w.y; Ry.z += w.z; Ry.w += w.w;
  }
  double sx = (double)Rx.x + Rx.y + Rx.z + Rx.w;
  double sy = (double)Ry.x + Ry.y + Ry.z + Ry.w;
  double srr = (double)Rx.x * Ry.x + (double)Rx.y * Ry.y + (double)Rx.z * Ry.z + (double)Rx.w * Ry.w;
  double sxx = (double)Rx.x * Rx.x + (double)Rx.y * Rx.y + (double)Rx.z * Rx.z + (double)Rx.w * Rx.w;
  double syy = (double)Ry.x * Ry.x + (double)Ry.y * Ry.y + (double)Ry.z * Ry.z + (double)Ry.w * Ry.w;
  double ab = (double)pab[tid];   // 256 partials, 256 threads
  double aa = (double)paa[tid];
  double bb = (double)pbb[tid];
  #pragma unroll
  for (int o = 32; o > 0; o >>= 1) {
    sx += __shfl_down(sx, o, 64);  sy += __shfl_down(sy, o, 64);
    srr += __shfl_down(srr, o, 64); sxx += __shfl_down(sxx, o, 64);
    syy += __shfl_down(syy, o, 64); ab += __shfl_down(ab, o, 64);
    aa += __shfl_down(aa, o, 64);  bb += __shfl_down(bb, o, 64);
  }
  __shared__ double t[8][4];
  int lane = tid & 63, w = tid >> 6;
  if (lane == 0) {
    t[0][w] = sx; t[1][w] = sy; t[2][w] = srr; t[3][w] = sxx;
    t[4][w] = syy; t[5][w] = ab; t[6][w] = aa; t[7][w] = bb;
  }
  __syncthreads();
  if (tid == 0) {
    sx  = t[0][0] + t[0][1] + t[0][2] + t[0][3];
    sy  = t[1][0] + t[1][1] + t[1][2] + t[1][3];
    srr = t[2][0] + t[2][1] + t[2][2] + t[2][3];
    sxx = t[3][0] + t[3][1] + t[3][2] + t[3][3];
    syy = t[4][0] + t[4][1] + t[4][2] + t[4][3];
    ab  = t[5][0] + t[5][1] + t[5][2] + t[5][3];
    aa  = t[6][0] + t[6][1] + t[6][2] + t[6][3];
    bb  = t[7][0] + t[7][1] + t[7][2] + t[7][3];
    const double n = (double)NN, n2 = n * n;
    double AB = ab - (2.0 / n) * srr + sx * sy / n2;
    double AA = aa - (2.0 / n) * sxx + sx * sx / n2;
    double BB = bb - (2.0 / n) * syy + sy * sy / n2;
    double xy = AB / n2, xx = AA / n2, yy = BB / n2;
    double r = xy / sqrt(xx * yy + 1e-9);
    out[0] = (float)(1.0 - r);
  }
}

extern "C" void kernel_launch(void* const* d_in, const int* in_sizes, int n_in,
                              void* d_out, int out_size, void* d_ws, size_t ws_size,
                              hipStream_t stream) {
  const float* in0 = (const float*)d_in[0];   // output_1 (N,T,C) fp32
  const float* in1 = (const float*)d_in[1];   // feature  (N,T,C) fp32

  char* ws = (char*)d_ws;
  float* x   = (float*)(ws);                          // 1 MB
  float* y   = (float*)(ws + (1u << 20));             // 1 MB
  float* nx  = (float*)(ws + (2u << 20));             // 4 KB
  float* ny  = (float*)(ws + (2u << 20) + 4096);      // 4 KB
  float* Rxp = (float*)(ws + (2u << 20) + 8192);      // 64 KB (16x1024)
  float* Ryp = (float*)(ws + (2u << 20) + 8192 + 65536);        // 64 KB
  float* pab = (float*)(ws + (2u << 20) + 8192 + 2 * 65536);    // 1 KB
  float* paa = (float*)(ws + (2u << 20) + 8192 + 2 * 65536 + 1024);
  float* pbb = (float*)(ws + (2u << 20) + 8192 + 2 * 65536 + 2048);

  mean_norm_kernel<<<2 * NN, 256, 0, stream>>>(in0, in1, x, y, nx, ny);
  dist_kernel<<<dim3(16, 16), 512, 0, stream>>>(x, y, nx, ny, Rxp, Ryp, pab, paa, pbb);
  finalize_kernel<<<1, 256, 0, stream>>>(Rxp, Ryp, pab, paa, pbb, (float*)d_out);
}